// Round 3
// baseline (1109.474 us; speedup 1.0000x reference)
//
#include <hip/hip_runtime.h>

// GCNStoModel_MultiHead: 2-layer GraphSAGE-GCN + linear head.
// IN=128, HID=256, OUT=256, PHEAD=64
// N0=1048576, E0=2097152, ND0=131072, E1=131072, ND1=8192, task_index=0.
//
// R1: CSR build + gather aggregation (no float atomics).
// R2: agg latency fix — cooperative edge-index load + __shfl broadcast +
//     8-deep software-pipelined gathers.
// R3: dead-row elimination (needed-mask; only ~66% of ND0 rows consumed).
// R4: fuse agg0+gemm1. One block per 64 needed rows: gather/aggregate into
//     a 64x128 LDS tile (scaled by 1/deg), then mini-GEMM vs W1 (staged in
//     32-k LDS chunks) with bias+ReLU, writing h1 at ORIGINAL row indices.
//     Eliminates the neigh0c/deg0c round-trip (44 MB write + ~176 MB read),
//     overlaps GEMM VALU with gather memory stalls, and drops the rank
//     remap (rows_list built directly in the needed-scan's final pass).

#define GEMM_BM 64
#define GEMM_BN 64
#define GEMM_BK 32
#define FBM 64   // rows per fused block

// ---------------------------------------------------------------------------
// needed[i]=1 for i<ND1 and for every i in src1. (benign write races)
__global__ __launch_bounds__(256) void mark_kernel(const int* __restrict__ src1,
                                                   int* __restrict__ needed,
                                                   int E, int nd1) {
    int e = blockIdx.x * 256 + threadIdx.x;
    if (e < nd1) needed[e] = 1;
    if (e >= E) return;
    needed[src1[e]] = 1;
}

// CSR build step 1: count[d] = #edges with dst==d   (count pre-zeroed)
__global__ __launch_bounds__(256) void hist_kernel(const int* __restrict__ dst,
                                                   const int* __restrict__ needed,
                                                   int* __restrict__ count, int E) {
    int e = blockIdx.x * 256 + threadIdx.x;
    if (e >= E) return;
    int d = dst[e];
    if (needed != nullptr && needed[d] == 0) return;
    atomicAdd(&count[d], 1);
}

// CSR build step 2a: per-block (1024-elem) sums
__global__ __launch_bounds__(256) void block_sum_kernel(const int* __restrict__ count,
                                                        int* __restrict__ bsum) {
    __shared__ int sdata[256];
    int t = threadIdx.x;
    int i = blockIdx.x * 1024 + t * 4;
    int s = count[i] + count[i + 1] + count[i + 2] + count[i + 3];
    sdata[t] = s;
    __syncthreads();
    for (int off = 128; off > 0; off >>= 1) {
        if (t < off) sdata[t] += sdata[t + off];
        __syncthreads();
    }
    if (t == 0) bsum[blockIdx.x] = sdata[0];
}

// CSR build step 2b: exclusive scan of nb block sums (nb <= 256), one block.
// Optionally writes the grand total to *total.
__global__ __launch_bounds__(256) void scan_small_kernel(const int* __restrict__ bsum,
                                                         int* __restrict__ boff, int nb,
                                                         int* __restrict__ total) {
    __shared__ int sdata[256];
    int t = threadIdx.x;
    int v = (t < nb) ? bsum[t] : 0;
    sdata[t] = v;
    __syncthreads();
    int val = v;
    for (int off = 1; off < 256; off <<= 1) {
        int x = (t >= off) ? sdata[t - off] : 0;
        __syncthreads();
        val += x;
        sdata[t] = val;
        __syncthreads();
    }
    if (t < nb) boff[t] = val - v;  // exclusive
    if (total != nullptr && t == nb - 1) *total = val;
}

// CSR build step 2c: final exclusive scan -> row_start (and cursor copy)
__global__ __launch_bounds__(256) void scan_final_kernel(const int* __restrict__ count,
                                                         const int* __restrict__ boff,
                                                         int* __restrict__ row_start,
                                                         int* __restrict__ cursor) {
    __shared__ int sdata[256];
    int t = threadIdx.x;
    int base_i = blockIdx.x * 1024 + t * 4;
    int c0 = count[base_i], c1 = count[base_i + 1], c2 = count[base_i + 2], c3 = count[base_i + 3];
    int local = c0 + c1 + c2 + c3;
    sdata[t] = local;
    __syncthreads();
    int val = local;
    for (int off = 1; off < 256; off <<= 1) {
        int x = (t >= off) ? sdata[t - off] : 0;
        __syncthreads();
        val += x;
        sdata[t] = val;
        __syncthreads();
    }
    int base = boff[blockIdx.x] + (val - local);  // exclusive prefix
    int r0 = base, r1 = r0 + c0, r2 = r1 + c1, r3 = r2 + c2;
    row_start[base_i] = r0; row_start[base_i + 1] = r1;
    row_start[base_i + 2] = r2; row_start[base_i + 3] = r3;
    cursor[base_i] = r0; cursor[base_i + 1] = r1;
    cursor[base_i + 2] = r2; cursor[base_i + 3] = r3;
}

// R4: scan over needed-mask; emits the compacted row list directly:
// rows_list[rank(i)] = i for every needed i.
__global__ __launch_bounds__(256) void scan_final_rank_kernel(const int* __restrict__ needed,
                                                              const int* __restrict__ boff,
                                                              int* __restrict__ rows_list) {
    __shared__ int sdata[256];
    int t = threadIdx.x;
    int base_i = blockIdx.x * 1024 + t * 4;
    int c0 = needed[base_i], c1 = needed[base_i + 1], c2 = needed[base_i + 2], c3 = needed[base_i + 3];
    int local = c0 + c1 + c2 + c3;
    sdata[t] = local;
    __syncthreads();
    int val = local;
    for (int off = 1; off < 256; off <<= 1) {
        int x = (t >= off) ? sdata[t - off] : 0;
        __syncthreads();
        val += x;
        sdata[t] = val;
        __syncthreads();
    }
    int r = boff[blockIdx.x] + (val - local);  // exclusive prefix = rank
    if (c0) rows_list[r] = base_i;     r += c0;
    if (c1) rows_list[r] = base_i + 1; r += c1;
    if (c2) rows_list[r] = base_i + 2; r += c2;
    if (c3) rows_list[r] = base_i + 3; r += c3;
}

// CSR build step 3: bucket edges by dst (skip un-needed dst rows).
__global__ __launch_bounds__(256) void fill_kernel(const int* __restrict__ src,
                                                   const int* __restrict__ dst,
                                                   const int* __restrict__ needed,
                                                   int* __restrict__ cursor,
                                                   int* __restrict__ edge_src, int E) {
    int e = blockIdx.x * 256 + threadIdx.x;
    if (e >= E) return;
    int d = dst[e];
    if (needed != nullptr && needed[d] == 0) return;
    int p = atomicAdd(&cursor[d], 1);
    edge_src[p] = src[e];
}

// ---------------------------------------------------------------------------
// R4 fused layer-0: per block, gather+aggregate 64 needed rows of x into LDS
// (scaled by 1/(deg+1)), then C[64][256] = rows @ W1^T + b1, ReLU, written to
// h1 at the rows' ORIGINAL indices.
__global__ __launch_bounds__(256) void agg_gemm0_kernel(const float* __restrict__ x,
                                                        const int* __restrict__ rows_list,
                                                        const int* __restrict__ nr_ptr,
                                                        const int* __restrict__ row_start,
                                                        const int* __restrict__ count,
                                                        const int* __restrict__ edge_src,
                                                        const float* __restrict__ W1,  // [256][128]
                                                        const float* __restrict__ b1,  // [256]
                                                        float* __restrict__ h1) {      // [ND0][256]
    __shared__ float rows[FBM][129];   // [m][k], pad 129: ~2-way banks both phases
    __shared__ float Ws[32][256];      // [k][n] chunk of W1^T
    __shared__ int widx[FBM];

    const int nr = *nr_ptr;
    const int row0 = blockIdx.x * FBM;
    if (row0 >= nr) return;            // uniform; before any __syncthreads

    const int t = threadIdx.x;
    const int lane = t & 63;
    const int wv = t >> 6;             // wave 0..3

    // ---- gather phase: wave wv aggregates rows m = wv*16 .. wv*16+15 ----
    for (int i = 0; i < 16; ++i) {
        const int m = wv * 16 + i;
        const int w = rows_list[min(row0 + m, nr - 1)];  // clamp: dup of last row
        if (lane == 0) widx[m] = w;
        float2 gacc = *(const float2*)(x + (size_t)w * 128 + (size_t)lane * 2);
        const int rs = row_start[w];
        const int cnt = count[w];

        for (int base = 0; base < cnt; base += 64) {
            const int rem = min(cnt - base, 64);             // >= 1
            const int idx = edge_src[rs + base + min(lane, rem - 1)];
            for (int jj = 0; jj < rem; jj += 8) {
                int s[8];
                float mk[8];
                #pragma unroll
                for (int k = 0; k < 8; ++k) {
                    int j = jj + k;
                    s[k] = __shfl(idx, min(j, rem - 1));
                    mk[k] = (j < rem) ? 1.0f : 0.0f;
                }
                float2 v[8];
                #pragma unroll
                for (int k = 0; k < 8; ++k)
                    v[k] = *(const float2*)(x + (size_t)s[k] * 128 + (size_t)lane * 2);
                #pragma unroll
                for (int k = 0; k < 8; ++k) {
                    gacc.x += v[k].x * mk[k];
                    gacc.y += v[k].y * mk[k];
                }
            }
        }
        const float s = 1.0f / (float)(cnt + 1);
        rows[m][lane * 2 + 0] = gacc.x * s;
        rows[m][lane * 2 + 1] = gacc.y * s;
    }
    __syncthreads();  // rows + widx complete

    // ---- GEMM phase: thread tile 4 rows x 16 cols ----
    const int tm = (t & 15) * 4;
    const int tn = (t >> 4) * 16;
    float acc[4][16] = {};

    for (int kc = 0; kc < 128; kc += 32) {
        // stage Ws[k][n] = W1[n][kc+k]; thread t owns column n = t
        {
            const float* srcp = W1 + (size_t)t * 128 + kc;
            #pragma unroll
            for (int j = 0; j < 8; ++j) {
                float4 v = *(const float4*)(srcp + j * 4);
                Ws[j * 4 + 0][t] = v.x; Ws[j * 4 + 1][t] = v.y;
                Ws[j * 4 + 2][t] = v.z; Ws[j * 4 + 3][t] = v.w;
            }
        }
        __syncthreads();
        #pragma unroll 8
        for (int k = 0; k < 32; ++k) {
            const int kk = kc + k;
            float a0 = rows[tm + 0][kk];
            float a1 = rows[tm + 1][kk];
            float a2 = rows[tm + 2][kk];
            float a3 = rows[tm + 3][kk];
            #pragma unroll
            for (int q = 0; q < 4; ++q) {
                const float4 wv4 = *(const float4*)&Ws[k][tn + q * 4];
                acc[0][q * 4 + 0] += a0 * wv4.x; acc[0][q * 4 + 1] += a0 * wv4.y;
                acc[0][q * 4 + 2] += a0 * wv4.z; acc[0][q * 4 + 3] += a0 * wv4.w;
                acc[1][q * 4 + 0] += a1 * wv4.x; acc[1][q * 4 + 1] += a1 * wv4.y;
                acc[1][q * 4 + 2] += a1 * wv4.z; acc[1][q * 4 + 3] += a1 * wv4.w;
                acc[2][q * 4 + 0] += a2 * wv4.x; acc[2][q * 4 + 1] += a2 * wv4.y;
                acc[2][q * 4 + 2] += a2 * wv4.z; acc[2][q * 4 + 3] += a2 * wv4.w;
                acc[3][q * 4 + 0] += a3 * wv4.x; acc[3][q * 4 + 1] += a3 * wv4.y;
                acc[3][q * 4 + 2] += a3 * wv4.z; acc[3][q * 4 + 3] += a3 * wv4.w;
            }
        }
        __syncthreads();  // before next chunk overwrites Ws
    }

    // ---- epilogue: bias + relu + scatter-store to original row indices ----
    float bb[16];
    #pragma unroll
    for (int q = 0; q < 4; ++q) {
        const float4 b4 = *(const float4*)(b1 + tn + q * 4);
        bb[q * 4 + 0] = b4.x; bb[q * 4 + 1] = b4.y;
        bb[q * 4 + 2] = b4.z; bb[q * 4 + 3] = b4.w;
    }
    #pragma unroll
    for (int i = 0; i < 4; ++i) {
        const int w = widx[tm + i];
        float* dstp = h1 + (size_t)w * 256 + tn;
        #pragma unroll
        for (int q = 0; q < 4; ++q) {
            float4 r;
            r.x = fmaxf(acc[i][q * 4 + 0] + bb[q * 4 + 0], 0.0f);
            r.y = fmaxf(acc[i][q * 4 + 1] + bb[q * 4 + 1], 0.0f);
            r.z = fmaxf(acc[i][q * 4 + 2] + bb[q * 4 + 2], 0.0f);
            r.w = fmaxf(acc[i][q * 4 + 3] + bb[q * 4 + 3], 0.0f);
            *(float4*)(dstp + q * 4) = r;
        }
    }
}

// ---------------------------------------------------------------------------
// gather aggregation (layer 1): one wave per dst row; RF floats/lane.
template<int RF> struct VecSel;
template<> struct VecSel<2> { using V = float2; };
template<> struct VecSel<4> { using V = float4; };

template<int RF>
__global__ __launch_bounds__(256) void agg_kernel(const float* __restrict__ feat,
                                                  const float* __restrict__ selff,
                                                  const int* __restrict__ row_start,
                                                  const int* __restrict__ count,
                                                  const int* __restrict__ edge_src,
                                                  float* __restrict__ neigh,
                                                  float* __restrict__ deg, int ND) {
    using V = typename VecSel<RF>::V;
    int w = (blockIdx.x * 256 + threadIdx.x) >> 6;  // wave id == dst row
    int lane = threadIdx.x & 63;
    if (w >= ND) return;
    const int K = 64 * RF;
    size_t lo = (size_t)w * K + (size_t)lane * RF;
    V acc = *(const V*)(selff + lo);
    const int rs = row_start[w];
    const int cnt = count[w];

    for (int base = 0; base < cnt; base += 64) {
        const int rem = min(cnt - base, 64);
        const int idx = edge_src[rs + base + min(lane, rem - 1)];
        for (int jj = 0; jj < rem; jj += 8) {
            int s[8];
            float m[8];
            #pragma unroll
            for (int k = 0; k < 8; ++k) {
                int j = jj + k;
                s[k] = __shfl(idx, min(j, rem - 1));
                m[k] = (j < rem) ? 1.0f : 0.0f;
            }
            V v[8];
            #pragma unroll
            for (int k = 0; k < 8; ++k)
                v[k] = *(const V*)(feat + (size_t)s[k] * K + (size_t)lane * RF);
            #pragma unroll
            for (int k = 0; k < 8; ++k) {
                acc.x += v[k].x * m[k];
                acc.y += v[k].y * m[k];
                if constexpr (RF == 4) {
                    acc.z += v[k].z * m[k];
                    acc.w += v[k].w * m[k];
                }
            }
        }
    }
    *(V*)(neigh + lo) = acc;
    if (lane == 0) deg[w] = (float)(cnt + 1);
}

// ---------------------------------------------------------------------------
// C[M,N] = act( (A * rowscale) @ W^T + b ), fp32, 64x64x32 tiles, 4x4/thread.
template<bool RELU, bool HAS_RS>
__global__ __launch_bounds__(256) void gemm_kernel(const float* __restrict__ A,    // M x K
                                                   const float* __restrict__ deg,  // M or null
                                                   const float* __restrict__ W,    // N x K
                                                   const float* __restrict__ bias, // N
                                                   float* __restrict__ C,          // M x N
                                                   int N, int K) {
    __shared__ float As[GEMM_BK][GEMM_BM];  // [k][m]
    __shared__ float Ws[GEMM_BK][GEMM_BN];  // [k][n]

    const int t = threadIdx.x;
    const int row0 = blockIdx.x * GEMM_BM;
    const int col0 = blockIdx.y * GEMM_BN;

    const int tm = (t & 15) * 4;
    const int tn = (t >> 4) * 4;

    float acc[4][4] = {};

    const int lr = t >> 3;       // 0..31
    const int lk = (t & 7) * 4;  // 0,4,...,28

    for (int k0 = 0; k0 < K; k0 += GEMM_BK) {
        #pragma unroll
        for (int pass = 0; pass < 2; ++pass) {
            int r = lr + pass * 32;
            const float4 v = *(const float4*)(A + (size_t)(row0 + r) * K + k0 + lk);
            As[lk + 0][r] = v.x; As[lk + 1][r] = v.y;
            As[lk + 2][r] = v.z; As[lk + 3][r] = v.w;
        }
        #pragma unroll
        for (int pass = 0; pass < 2; ++pass) {
            int n = lr + pass * 32;
            const float4 v = *(const float4*)(W + (size_t)(col0 + n) * K + k0 + lk);
            Ws[lk + 0][n] = v.x; Ws[lk + 1][n] = v.y;
            Ws[lk + 2][n] = v.z; Ws[lk + 3][n] = v.w;
        }
        __syncthreads();

        #pragma unroll
        for (int k = 0; k < GEMM_BK; ++k) {
            const float4 a = *(const float4*)&As[k][tm];
            const float4 w = *(const float4*)&Ws[k][tn];
            acc[0][0] += a.x * w.x; acc[0][1] += a.x * w.y; acc[0][2] += a.x * w.z; acc[0][3] += a.x * w.w;
            acc[1][0] += a.y * w.x; acc[1][1] += a.y * w.y; acc[1][2] += a.y * w.z; acc[1][3] += a.y * w.w;
            acc[2][0] += a.z * w.x; acc[2][1] += a.z * w.y; acc[2][2] += a.z * w.z; acc[2][3] += a.z * w.w;
            acc[3][0] += a.w * w.x; acc[3][1] += a.w * w.y; acc[3][2] += a.w * w.z; acc[3][3] += a.w * w.w;
        }
        __syncthreads();
    }

    float scl[4];
    #pragma unroll
    for (int i = 0; i < 4; ++i)
        scl[i] = HAS_RS ? (1.0f / deg[row0 + tm + i]) : 1.0f;

    float bb[4];
    #pragma unroll
    for (int j = 0; j < 4; ++j) bb[j] = bias[col0 + tn + j];

    #pragma unroll
    for (int i = 0; i < 4; ++i) {
        float4 v;
        v.x = acc[i][0] * scl[i] + bb[0];
        v.y = acc[i][1] * scl[i] + bb[1];
        v.z = acc[i][2] * scl[i] + bb[2];
        v.w = acc[i][3] * scl[i] + bb[3];
        if (RELU) {
            v.x = fmaxf(v.x, 0.0f); v.y = fmaxf(v.y, 0.0f);
            v.z = fmaxf(v.z, 0.0f); v.w = fmaxf(v.w, 0.0f);
        }
        *(float4*)(C + (size_t)(row0 + tm + i) * N + col0 + tn) = v;
    }
}

// ---------------------------------------------------------------------------
extern "C" void kernel_launch(void* const* d_in, const int* in_sizes, int n_in,
                              void* d_out, int out_size, void* d_ws, size_t ws_size,
                              hipStream_t stream) {
    const float* x   = (const float*)d_in[0];
    const int* src0  = (const int*)d_in[1];
    const int* dst0  = (const int*)d_in[2];
    const int* src1  = (const int*)d_in[3];
    const int* dst1  = (const int*)d_in[4];
    const float* W1  = (const float*)d_in[5];
    const float* b1  = (const float*)d_in[6];
    const float* W2  = (const float*)d_in[7];
    const float* b2  = (const float*)d_in[8];
    const float* Wh  = (const float*)d_in[9];
    const float* bh  = (const float*)d_in[10];

    const int E0 = in_sizes[1];
    const int E1 = in_sizes[3];
    const int HID = 256, OUT = 256, PHEAD = 64;
    const int ND0 = 131072, ND1 = 8192;

    // ---- workspace layout (non-overlapping; ~165 MB) ----
    float* ws = (float*)d_ws;
    float* h1     = ws;                               // ND0*HID = 128 MB (needed rows only written)
    float* neigh1 = h1 + (size_t)ND0 * HID;           // ND1*HID
    float* deg1   = neigh1 + (size_t)ND1 * HID;       // ND1
    float* h2     = deg1 + ND1;                       // ND1*OUT
    float* out    = (float*)d_out;                    // ND1*PHEAD

    // count0, needed, count1 contiguous -> zeroed in ONE memset
    int* count0     = (int*)(h2 + (size_t)ND1 * OUT); // ND0
    int* needed     = count0 + ND0;                   // ND0
    int* count1     = needed + ND0;                   // ND1
    int* rows_list  = count1 + ND1;                   // ND0 (first nr valid)
    int* row_start0 = rows_list + ND0;                // ND0
    int* cursor0    = row_start0 + ND0;               // ND0
    int* edge_src0  = cursor0 + ND0;                  // E0
    int* row_start1 = edge_src0 + E0;                 // ND1
    int* cursor1    = row_start1 + ND1;               // ND1
    int* edge_src1  = cursor1 + ND1;                  // E1
    int* bsumA      = edge_src1 + E1;                 // 256
    int* boffA      = bsumA + 256;                    // 256
    int* bsumB      = boffA + 256;                    // 256
    int* boffB      = bsumB + 256;                    // 256
    int* nr_ptr     = boffB + 256;                    // 1: needed row count

    hipMemsetAsync(count0, 0, (size_t)(2 * ND0 + ND1) * sizeof(int), stream);

    // ---- needed-mask + rows_list (compacted needed-row indices) ----
    mark_kernel<<<E1 / 256, 256, 0, stream>>>(src1, needed, E1, ND1);
    block_sum_kernel<<<ND0 / 1024, 256, 0, stream>>>(needed, bsumA);
    scan_small_kernel<<<1, 256, 0, stream>>>(bsumA, boffA, ND0 / 1024, nr_ptr);
    scan_final_rank_kernel<<<ND0 / 1024, 256, 0, stream>>>(needed, boffA, rows_list);

    // ---- layer 0: CSR build (needed rows only) + fused agg+GEMM ----
    hist_kernel<<<E0 / 256, 256, 0, stream>>>(dst0, needed, count0, E0);
    block_sum_kernel<<<ND0 / 1024, 256, 0, stream>>>(count0, bsumB);
    scan_small_kernel<<<1, 256, 0, stream>>>(bsumB, boffB, ND0 / 1024, nullptr);
    scan_final_kernel<<<ND0 / 1024, 256, 0, stream>>>(count0, boffB, row_start0, cursor0);
    fill_kernel<<<E0 / 256, 256, 0, stream>>>(src0, dst0, needed, cursor0, edge_src0, E0);
    agg_gemm0_kernel<<<ND0 / FBM, 256, 0, stream>>>(x, rows_list, nr_ptr, row_start0,
                                                    count0, edge_src0, W1, b1, h1);

    // ---- layer 1 (h1 indexed by ORIGINAL row ids; rows < ND1 all needed) ----
    hist_kernel<<<E1 / 256, 256, 0, stream>>>(dst1, nullptr, count1, E1);
    block_sum_kernel<<<ND1 / 1024, 256, 0, stream>>>(count1, bsumB);
    scan_small_kernel<<<1, 256, 0, stream>>>(bsumB, boffB, ND1 / 1024, nullptr);
    scan_final_kernel<<<ND1 / 1024, 256, 0, stream>>>(count1, boffB, row_start1, cursor1);
    fill_kernel<<<E1 / 256, 256, 0, stream>>>(src1, dst1, nullptr, cursor1, edge_src1, E1);
    agg_kernel<4><<<ND1 / 4, 256, 0, stream>>>(h1, h1, row_start1, count1, edge_src1,
                                               neigh1, deg1, ND1);
    {
        dim3 g(ND1 / GEMM_BM, OUT / GEMM_BN);
        gemm_kernel<true, true><<<g, 256, 0, stream>>>(neigh1, deg1, W2, b2, h2, OUT, HID);
    }

    // ---- head ----
    {
        dim3 g(ND1 / GEMM_BM, PHEAD / GEMM_BN);
        gemm_kernel<false, false><<<g, 256, 0, stream>>>(h2, nullptr, Wh, bh, out, PHEAD, OUT);
    }
}